// Round 2
// baseline (289.656 us; speedup 1.0000x reference)
//
#include <hip/hip_runtime.h>
#include <hip/hip_fp16.h>
#include <math.h>

// GAT encoder: N=10000, E=160000 (+N self loops), H=8 heads, C=128, D=1024.
// R17: dispatch fusion 16->11 (prep, scan||scoresX, scoresP folded into tails).
// R18: per-layer megafusion 11->7 dispatches. attnagg + tail share one
// 512-thread block (32 nodes): Y tile lives in LDS (no Y16/Y1 global round
// trip, -82MB traffic). Stage-1 overwrites the Y tile in place (each wave
// owns a 128-col stripe, loads its B-fragments to regs first). Cross-block
// races from fusion fixed with ping-pong buffers: ssrcA/B, P16a/b.

#define THREADS 256

typedef _Float16 f16x8 __attribute__((ext_vector_type(8)));
typedef float f32x4 __attribute__((ext_vector_type(4)));

struct __align__(8) Half4 { __half2 a, b; };

__device__ __forceinline__ float gelu_exact(float x) {
  return 0.5f * x * (1.0f + erff(x * 0.70710678118654752f));
}

// ---------------- fused prep: hist + weight transpose/convert + score-vectors ----------------

__global__ __launch_bounds__(256) void prep_kernel(
    const int* __restrict__ ei, int E, int ET, int* __restrict__ counts,
    const float* __restrict__ w2, const float* __restrict__ w3,
    const float* __restrict__ rw1, const float* __restrict__ rw2,
    const float* __restrict__ lw,
    __half* __restrict__ wt2, __half* __restrict__ wt3,
    __half* __restrict__ rwt1, __half* __restrict__ rwt2,
    __half* __restrict__ lwt,
    const float* __restrict__ w1,
    const float* __restrict__ as1, const float* __restrict__ ad1,
    const float* __restrict__ as2, const float* __restrict__ ad2,
    const float* __restrict__ as3, const float* __restrict__ ad3,
    float* __restrict__ ws1, float* __restrict__ wd1,
    float* __restrict__ ws2, float* __restrict__ wd2,
    float* __restrict__ ws3, float* __restrict__ wd3,
    int nHist) {
  __shared__ float tile[32][33];
  int bid = blockIdx.x;
  int t = threadIdx.x;

  if (bid < nHist) {
    int e = bid * 256 + t;
    if (e >= ET) return;
    int d = (e < E) ? ei[E + e] : (e - E);
    atomicAdd(&counts[d], 1);
    return;
  }
  bid -= nHist;
  if (bid < 640) {
    const float* in; __half* out; int K, Ncol;
    int z = bid >> 7, rem = bid & 127;
    switch (z) {
      case 0: in = w2;  out = wt2;  K = 128;  Ncol = 1024; break;
      case 1: in = w3;  out = wt3;  K = 128;  Ncol = 1024; break;
      case 2: in = rw1; out = rwt1; K = 1024; Ncol = 128;  break;
      case 3: in = rw2; out = rwt2; K = 1024; Ncol = 128;  break;
      default: in = lw; out = lwt;  K = 1024; Ncol = 128;  break;
    }
    int kt, ct;
    if (z < 2) { kt = rem >> 5; ct = rem & 31; }
    else       { kt = rem & 31; ct = rem >> 5; }
    int kb = kt * 32, cb = ct * 32;
    int tc = t & 31, tr = t >> 5;
#pragma unroll
    for (int r = tr; r < 32; r += 8)
      tile[r][tc] = in[(size_t)(kb + r) * Ncol + cb + tc];
    __syncthreads();
#pragma unroll
    for (int r = tr; r < 32; r += 8)
      out[(size_t)(cb + r) * K + kb + tc] = __float2half_rn(tile[tc][r]);
    return;
  }
  bid -= 640;
  {
    int h = bid & 7, yy = bid >> 3;
    int sel = t >> 7;
    int k = t & 127;
    const float* W; const float* av; float* outp; int K;
    switch (yy) {
      case 0: W = w2; av = sel ? ad2 : as2; outp = sel ? wd2 : ws2; K = 128; break;
      case 1: W = w3; av = sel ? ad3 : as3; outp = sel ? wd3 : ws3; K = 128; break;
      default: W = w1; av = sel ? ad1 : as1; outp = sel ? wd1 : ws1; K = 4; break;
    }
    if (k >= K) return;
    const float* wrow = W + (size_t)k * 1024 + h * 128;
    const float* arow = av + h * 128;
    float s = 0.f;
    for (int c = 0; c < 128; c += 4) {
      float4 wv = *(const float4*)&wrow[c];
      float4 a4 = *(const float4*)&arow[c];
      s += wv.x * a4.x + wv.y * a4.y + wv.z * a4.z + wv.w * a4.w;
    }
    outp[h * K + k] = s;
  }
}

// ---------------- scan (block 0) || layer-1 scores (blocks 1..) ----------------

__global__ __launch_bounds__(1024) void scan_scores_kernel(
    const int* __restrict__ counts, int* __restrict__ offsets,
    int* __restrict__ cursor, int n,
    const float* __restrict__ x,
    const float* __restrict__ ws1, const float* __restrict__ wd1,
    float* __restrict__ ssrc, float* __restrict__ sdst, int total) {
  __shared__ int sums[1024];
  if (blockIdx.x == 0) {
    int t = threadIdx.x;
    int per = (n + 1023) >> 10;
    int start = t * per; if (start > n) start = n;
    int end = start + per; if (end > n) end = n;
    int local = 0;
    for (int i = start; i < end; ++i) local += counts[i];
    sums[t] = local;
    __syncthreads();
    for (int off = 1; off < 1024; off <<= 1) {
      int add = (t >= off) ? sums[t - off] : 0;
      __syncthreads();
      sums[t] += add;
      __syncthreads();
    }
    int run = (t == 0) ? 0 : sums[t - 1];
    for (int i = start; i < end; ++i) {
      offsets[i] = run; cursor[i] = run; run += counts[i];
    }
    if (t == 1023) offsets[n] = run;
    return;
  }
  int idx = (blockIdx.x - 1) * 1024 + threadIdx.x;
  if (idx >= total) return;
  int nn = idx >> 3, h = idx & 7;
  float4 xv = *(const float4*)&x[nn * 4];
  float4 a = *(const float4*)&ws1[h * 4];
  float4 b = *(const float4*)&wd1[h * 4];
  ssrc[idx] = xv.x * a.x + xv.y * a.y + xv.z * a.z + xv.w * a.w;
  sdst[idx] = xv.x * b.x + xv.y * b.y + xv.z * b.z + xv.w * b.w;
}

__global__ void scatter_kernel(const int* __restrict__ ei, int E, int ET,
                               int* __restrict__ cursor, int* __restrict__ srcs) {
  int e = blockIdx.x * THREADS + threadIdx.x;
  if (e >= ET) return;
  int s = (e < E) ? ei[e] : (e - E);
  int d = (e < E) ? ei[E + e] : (e - E);
  int pos = atomicAdd(&cursor[d], 1);
  srcs[pos] = s;
}

// ---------------- fused layer 1: attnagg_x + dense tail, one block = 32 nodes ----------------

__global__ __launch_bounds__(512) void layer1_kernel(
    const float* __restrict__ x,
    const int* __restrict__ srcs, const int* __restrict__ offsets,
    const float* __restrict__ ssrc, const float* __restrict__ sdst,
    const float* __restrict__ w, const float* __restrict__ biasA,
    const __half* __restrict__ WtP, const float* __restrict__ biasP,
    __half* __restrict__ out, int N,
    const float* __restrict__ wsn, const float* __restrict__ wdn,
    float* __restrict__ ssrc_n, float* __restrict__ sdst_n) {
  __shared__ __half Gt[32][1032];
  __shared__ float Y1l[32][36];
  __shared__ __align__(16) char scratch[9216];   // lsc+lsi during attnagg; Pl later
  __shared__ float szinv[8][8];
  float (*lsc)[32][8] = reinterpret_cast<float(*)[32][8]>(scratch);
  int (*lsi)[32] = reinterpret_cast<int(*)[32]>(scratch + 8192);
  __half (*Pl)[136] = reinterpret_cast<__half(*)[136]>(scratch);

  int wv = threadIdx.x >> 6, lane = threadIdx.x & 63;
  int r0 = blockIdx.x * 32;
  int head = lane & 7, es = lane >> 3;
  int eo = lane >> 5, hb = (lane >> 2) & 7, ch = lane & 3;

  // ---- attention + aggregation for this wave's 4 nodes ----
  for (int j = 0; j < 4; ++j) {
    int row = wv * 4 + j, n = r0 + row;
    if (n >= N) {
      if (lane < 32) Y1l[row][hb * 4 + ch] = 0.f;
      continue;
    }
    int start = offsets[n], deg = offsets[n + 1] - start;
    float sd = sdst[n * 8 + head];
    float acc = 0.f, s = 0.f;
    for (int cc = 0; cc < deg; cc += 32) {
      int cm = min(32, deg - cc);
      for (int i = es; i < cm; i += 8) {
        int sp = srcs[start + cc + i];
        float v = ssrc[sp * 8 + head] + sd;
        v = (v > 0.f) ? v : 0.2f * v;
        float e = __expf(v);
        lsc[wv][i][head] = e;
        if (head == 0) lsi[wv][i] = sp;
        s += e;
      }
      for (int i = eo; i < cm; i += 2) {
        int sp = lsi[wv][i];
        acc += lsc[wv][i][hb] * x[sp * 4 + ch];
      }
    }
#pragma unroll
    for (int mask = 8; mask <= 32; mask <<= 1) s += __shfl_xor(s, mask);
    if (es == 0) szinv[wv][head] = 1.f / s;
    acc += __shfl_xor(acc, 32);
    if (lane < 32) Y1l[row][hb * 4 + ch] = acc * szinv[wv][hb];
  }
  __syncthreads();
  // ---- G = gelu(Y1 @ w + biasA) -> Gt ----
  {
    int t = threadIdx.x;
    int c0 = (t & 255) * 4;
    int h = c0 >> 7;
    float4 wa = *(const float4*)&w[c0];
    float4 wb = *(const float4*)&w[1024 + c0];
    float4 wc = *(const float4*)&w[2048 + c0];
    float4 wd = *(const float4*)&w[3072 + c0];
    float4 b4 = *(const float4*)&biasA[c0];
#pragma unroll 4
    for (int r = t >> 8; r < 32; r += 2) {
      float4 yv = *(const float4*)&Y1l[r][h * 4];
      float o0 = gelu_exact(yv.x * wa.x + yv.y * wb.x + yv.z * wc.x + yv.w * wd.x + b4.x);
      float o1 = gelu_exact(yv.x * wa.y + yv.y * wb.y + yv.z * wc.y + yv.w * wd.y + b4.y);
      float o2 = gelu_exact(yv.x * wa.z + yv.y * wb.z + yv.z * wc.z + yv.w * wd.z + b4.z);
      float o3 = gelu_exact(yv.x * wa.w + yv.y * wb.w + yv.z * wc.w + yv.w * wd.w + b4.w);
      Half4 p;
      p.a = __floats2half2_rn(o0, o1);
      p.b = __floats2half2_rn(o2, o3);
      *(Half4*)&Gt[r][c0] = p;
    }
  }
  __syncthreads();
  // ---- stage 2: out = G @ WtP^T + biasP ----
  int m = lane & 15, quad = lane >> 4;
  {
    int c0 = wv * 16;
    const __half* pa = WtP + (size_t)(c0 + m) * 1024 + quad * 8;
    f32x4 acc0 = {0.f, 0.f, 0.f, 0.f}, acc1 = {0.f, 0.f, 0.f, 0.f};
#pragma unroll 8
    for (int k = 0; k < 1024; k += 32) {
      f16x8 a = *(const f16x8*)(pa + k);
      f16x8 b0 = *(const f16x8*)&Gt[m][quad * 8 + k];
      f16x8 b1 = *(const f16x8*)&Gt[16 + m][quad * 8 + k];
      acc0 = __builtin_amdgcn_mfma_f32_16x16x32_f16(a, b0, acc0, 0, 0, 0);
      acc1 = __builtin_amdgcn_mfma_f32_16x16x32_f16(a, b1, acc1, 0, 0, 0);
    }
    float4 b4 = *(const float4*)&biasP[c0 + quad * 4];
    int row0 = r0 + m, row1 = r0 + 16 + m;
    Half4 p, q;
    p.a = __floats2half2_rn(acc0[0] + b4.x, acc0[1] + b4.y);
    p.b = __floats2half2_rn(acc0[2] + b4.z, acc0[3] + b4.w);
    q.a = __floats2half2_rn(acc1[0] + b4.x, acc1[1] + b4.y);
    q.b = __floats2half2_rn(acc1[2] + b4.z, acc1[3] + b4.w);
    *(Half4*)&Pl[m][c0 + quad * 4] = p;
    *(Half4*)&Pl[16 + m][c0 + quad * 4] = q;
    if (row0 < N) *(Half4*)&out[(size_t)row0 * 128 + c0 + quad * 4] = p;
    if (row1 < N) *(Half4*)&out[(size_t)row1 * 128 + c0 + quad * 4] = q;
  }
  __syncthreads();
  // ---- next-layer scores from Pl ----
  {
    const float* wsp = wsn + head * 128 + es * 16;
    const float* wdp = wdn + head * 128 + es * 16;
    float wsr[16], wdr[16];
#pragma unroll
    for (int j = 0; j < 16; ++j) { wsr[j] = wsp[j]; wdr[j] = wdp[j]; }
#pragma unroll
    for (int r = 0; r < 4; ++r) {
      int row = wv * 4 + r;
      f16x8 p0 = *(const f16x8*)&Pl[row][es * 16];
      f16x8 p1 = *(const f16x8*)&Pl[row][es * 16 + 8];
      float s1 = 0.f, s2 = 0.f;
#pragma unroll
      for (int j = 0; j < 8; ++j) {
        float v = (float)p0[j];
        s1 += v * wsr[j]; s2 += v * wdr[j];
      }
#pragma unroll
      for (int j = 0; j < 8; ++j) {
        float v = (float)p1[j];
        s1 += v * wsr[8 + j]; s2 += v * wdr[8 + j];
      }
#pragma unroll
      for (int mask = 8; mask <= 32; mask <<= 1) {
        s1 += __shfl_xor(s1, mask);
        s2 += __shfl_xor(s2, mask);
      }
      int nn = r0 + row;
      if (es == 0 && nn < N) { ssrc_n[nn * 8 + head] = s1; sdst_n[nn * 8 + head] = s2; }
    }
  }
}

// ---------------- fused layers 2/3: attnagg_p + MFMA tail, one block = 32 nodes ----------------
// attnagg writes the Y tile to LDS (Yl); stage 1 reads its wave's 128-col
// stripe into regs then overwrites Yl in place with G; stage 2 consumes G.

template <typename OutT, bool SC>
__global__ __launch_bounds__(512) void layer_p_kernel(
    const __half* __restrict__ P16,
    const int* __restrict__ srcs, const int* __restrict__ offsets,
    const float* __restrict__ ssrc, const float* __restrict__ sdst,
    const __half* __restrict__ WtA, const float* __restrict__ biasA,
    const __half* __restrict__ WtP, const float* __restrict__ biasP,
    OutT* __restrict__ out, int N,
    const float* __restrict__ wsn, const float* __restrict__ wdn,
    float* __restrict__ ssrc_n, float* __restrict__ sdst_n) {
  __shared__ __half Yl[32][1032];                 // Y tile, then G tile (in place)
  __shared__ __align__(16) char scratch[9216];   // lsc+lsi during attnagg; Pl later
  __shared__ float szinv[8][8];
  float (*lsc)[32][8] = reinterpret_cast<float(*)[32][8]>(scratch);
  int (*lsi)[32] = reinterpret_cast<int(*)[32]>(scratch + 8192);
  __half (*Pl)[136] = reinterpret_cast<__half(*)[136]>(scratch);

  int w = threadIdx.x >> 6, lane = threadIdx.x & 63;
  int r0 = blockIdx.x * 32;
  int head = lane & 7, es = lane >> 3;
  int c2 = lane * 2;
  int m = lane & 15, quad = lane >> 4;

  // ---- attention + aggregation for this wave's 4 nodes ----
  for (int j = 0; j < 4; ++j) {
    int row = w * 4 + j, n = r0 + row;
    if (n >= N) {
      __half2 z = __floats2half2_rn(0.f, 0.f);
#pragma unroll
      for (int h = 0; h < 8; ++h) *(__half2*)&Yl[row][h * 128 + c2] = z;
      continue;
    }
    int start = offsets[n], deg = offsets[n + 1] - start;
    float sd = sdst[n * 8 + head];
    float accx[8] = {}, accy[8] = {};
    float s = 0.f;
    for (int cc = 0; cc < deg; cc += 32) {
      int cm = min(32, deg - cc);
      for (int i = es; i < cm; i += 8) {
        int sp = srcs[start + cc + i];
        float v = ssrc[sp * 8 + head] + sd;
        v = (v > 0.f) ? v : 0.2f * v;
        float e = __expf(v);
        lsc[w][i][head] = e;
        if (head == 0) lsi[w][i] = sp;
        s += e;
      }
      int i = 0;
      for (; i + 1 < cm; i += 2) {
        int sp0 = lsi[w][i], sp1 = lsi[w][i + 1];
        float4 a00 = *(float4*)&lsc[w][i][0];
        float4 a01 = *(float4*)&lsc[w][i][4];
        float4 a10 = *(float4*)&lsc[w][i + 1][0];
        float4 a11 = *(float4*)&lsc[w][i + 1][4];
        float2 p0 = __half22float2(*(const __half2*)&P16[(size_t)sp0 * 128 + c2]);
        float2 p1 = __half22float2(*(const __half2*)&P16[(size_t)sp1 * 128 + c2]);
        float a0[8] = {a00.x, a00.y, a00.z, a00.w, a01.x, a01.y, a01.z, a01.w};
        float a1[8] = {a10.x, a10.y, a10.z, a10.w, a11.x, a11.y, a11.z, a11.w};
#pragma unroll
        for (int h = 0; h < 8; ++h) {
          accx[h] += a0[h] * p0.x; accy[h] += a0[h] * p0.y;
          accx[h] += a1[h] * p1.x; accy[h] += a1[h] * p1.y;
        }
      }
      if (i < cm) {
        int sp0 = lsi[w][i];
        float4 a00 = *(float4*)&lsc[w][i][0];
        float4 a01 = *(float4*)&lsc[w][i][4];
        float2 p0 = __half22float2(*(const __half2*)&P16[(size_t)sp0 * 128 + c2]);
        float a0[8] = {a00.x, a00.y, a00.z, a00.w, a01.x, a01.y, a01.z, a01.w};
#pragma unroll
        for (int h = 0; h < 8; ++h) {
          accx[h] += a0[h] * p0.x; accy[h] += a0[h] * p0.y;
        }
      }
    }
#pragma unroll
    for (int mask = 8; mask <= 32; mask <<= 1) s += __shfl_xor(s, mask);
    if (es == 0) szinv[w][head] = 1.f / s;
#pragma unroll
    for (int h = 0; h < 8; ++h) {
      float zi = szinv[w][h];
      *(__half2*)&Yl[row][h * 128 + c2] =
          __floats2half2_rn(accx[h] * zi, accy[h] * zi);
    }
  }
  __syncthreads();
  // ---- stage 1: G = gelu(Y @ WtA + biasA), overwriting Yl column stripe ----
  {
    int h = w;
    f16x8 bf0[4], bf1[4];
#pragma unroll
    for (int kk = 0; kk < 4; ++kk) {
      bf0[kk] = *(const f16x8*)&Yl[m][h * 128 + quad * 8 + kk * 32];
      bf1[kk] = *(const f16x8*)&Yl[16 + m][h * 128 + quad * 8 + kk * 32];
    }
#pragma unroll
    for (int tile = 0; tile < 8; ++tile) {
      int gc = h * 128 + tile * 16;
      const __half* pa = WtA + (size_t)(gc + m) * 128 + quad * 8;
      f16x8 a[4];
#pragma unroll
      for (int kk = 0; kk < 4; ++kk) a[kk] = *(const f16x8*)(pa + kk * 32);
      f32x4 acc0 = {0.f, 0.f, 0.f, 0.f}, acc1 = {0.f, 0.f, 0.f, 0.f};
#pragma unroll
      for (int kk = 0; kk < 4; ++kk) {
        acc0 = __builtin_amdgcn_mfma_f32_16x16x32_f16(a[kk], bf0[kk], acc0, 0, 0, 0);
        acc1 = __builtin_amdgcn_mfma_f32_16x16x32_f16(a[kk], bf1[kk], acc1, 0, 0, 0);
      }
      float4 b4 = *(const float4*)&biasA[gc + quad * 4];
      Half4 p0, p1;
      p0.a = __floats2half2_rn(gelu_exact(acc0[0] + b4.x), gelu_exact(acc0[1] + b4.y));
      p0.b = __floats2half2_rn(gelu_exact(acc0[2] + b4.z), gelu_exact(acc0[3] + b4.w));
      p1.a = __floats2half2_rn(gelu_exact(acc1[0] + b4.x), gelu_exact(acc1[1] + b4.y));
      p1.b = __floats2half2_rn(gelu_exact(acc1[2] + b4.z), gelu_exact(acc1[3] + b4.w));
      *(Half4*)&Yl[m][gc + quad * 4] = p0;
      *(Half4*)&Yl[16 + m][gc + quad * 4] = p1;
    }
  }
  __syncthreads();
  // ---- stage 2: out = G @ WtP^T + biasP ----
  {
    int c0 = w * 16;
    const __half* pa = WtP + (size_t)(c0 + m) * 1024 + quad * 8;
    f32x4 acc0 = {0.f, 0.f, 0.f, 0.f}, acc1 = {0.f, 0.f, 0.f, 0.f};
#pragma unroll 8
    for (int k = 0; k < 1024; k += 32) {
      f16x8 a = *(const f16x8*)(pa + k);
      f16x8 b0 = *(const f16x8*)&Yl[m][quad * 8 + k];
      f16x8 b1 = *(const f16x8*)&Yl[16 + m][quad * 8 + k];
      acc0 = __builtin_amdgcn_mfma_f32_16x16x32_f16(a, b0, acc0, 0, 0, 0);
      acc1 = __builtin_amdgcn_mfma_f32_16x16x32_f16(a, b1, acc1, 0, 0, 0);
    }
    float4 b4 = *(const float4*)&biasP[c0 + quad * 4];
    int row0 = r0 + m, row1 = r0 + 16 + m;
    if constexpr (__is_same(OutT, __half)) {
      Half4 p, q;
      p.a = __floats2half2_rn(acc0[0] + b4.x, acc0[1] + b4.y);
      p.b = __floats2half2_rn(acc0[2] + b4.z, acc0[3] + b4.w);
      q.a = __floats2half2_rn(acc1[0] + b4.x, acc1[1] + b4.y);
      q.b = __floats2half2_rn(acc1[2] + b4.z, acc1[3] + b4.w);
      if constexpr (SC) {
        *(Half4*)&Pl[m][c0 + quad * 4] = p;
        *(Half4*)&Pl[16 + m][c0 + quad * 4] = q;
      }
      if (row0 < N) *(Half4*)&out[(size_t)row0 * 128 + c0 + quad * 4] = p;
      if (row1 < N) *(Half4*)&out[(size_t)row1 * 128 + c0 + quad * 4] = q;
    } else {
      if (row0 < N)
        *(float4*)&out[(size_t)row0 * 128 + c0 + quad * 4] =
            make_float4(acc0[0] + b4.x, acc0[1] + b4.y, acc0[2] + b4.z, acc0[3] + b4.w);
      if (row1 < N)
        *(float4*)&out[(size_t)row1 * 128 + c0 + quad * 4] =
            make_float4(acc1[0] + b4.x, acc1[1] + b4.y, acc1[2] + b4.z, acc1[3] + b4.w);
    }
  }
  if constexpr (SC) {
    __syncthreads();
    // ---- next-layer scores from Pl ----
    const float* wsp = wsn + head * 128 + es * 16;
    const float* wdp = wdn + head * 128 + es * 16;
    float wsr[16], wdr[16];
#pragma unroll
    for (int j = 0; j < 16; ++j) { wsr[j] = wsp[j]; wdr[j] = wdp[j]; }
#pragma unroll
    for (int r = 0; r < 4; ++r) {
      int row = w * 4 + r;
      f16x8 p0 = *(const f16x8*)&Pl[row][es * 16];
      f16x8 p1 = *(const f16x8*)&Pl[row][es * 16 + 8];
      float s1 = 0.f, s2 = 0.f;
#pragma unroll
      for (int j = 0; j < 8; ++j) {
        float v = (float)p0[j];
        s1 += v * wsr[j]; s2 += v * wdr[j];
      }
#pragma unroll
      for (int j = 0; j < 8; ++j) {
        float v = (float)p1[j];
        s1 += v * wsr[8 + j]; s2 += v * wdr[8 + j];
      }
#pragma unroll
      for (int mask = 8; mask <= 32; mask <<= 1) {
        s1 += __shfl_xor(s1, mask);
        s2 += __shfl_xor(s2, mask);
      }
      int nn = r0 + row;
      if (es == 0 && nn < N) { ssrc_n[nn * 8 + head] = s1; sdst_n[nn * 8 + head] = s2; }
    }
  }
}

// ---------------- orchestration ----------------

extern "C" void kernel_launch(void* const* d_in, const int* in_sizes, int n_in,
                              void* d_out, int out_size, void* d_ws, size_t ws_size,
                              hipStream_t stream) {
  const float* x   = (const float*)d_in[0];
  const int*   ei  = (const int*)d_in[1];
  const float* w1  = (const float*)d_in[2];
  const float* as1 = (const float*)d_in[3];
  const float* ad1 = (const float*)d_in[4];
  const float* b1  = (const float*)d_in[5];
  const float* w2  = (const float*)d_in[6];
  const float* as2 = (const float*)d_in[7];
  const float* ad2 = (const float*)d_in[8];
  const float* b2  = (const float*)d_in[9];
  const float* w3  = (const float*)d_in[10];
  const float* as3 = (const float*)d_in[11];
  const float* ad3 = (const float*)d_in[12];
  const float* b3  = (const float*)d_in[13];
  const float* rw1 = (const float*)d_in[14];
  const float* rb1 = (const float*)d_in[15];
  const float* rw2 = (const float*)d_in[16];
  const float* rb2 = (const float*)d_in[17];
  const float* lw  = (const float*)d_in[18];
  const float* lb  = (const float*)d_in[19];

  int N = in_sizes[0] / 4;
  int E = in_sizes[1] / 2;
  int ET = E + N;
  int nRow32 = (N + 31) / 32;
  (void)ws_size;

  char* wsb = (char*)d_ws;
  size_t off = 0;
  auto alloc = [&](size_t bytes) -> void* {
    void* p = wsb + off;
    off += (bytes + 255) & ~(size_t)255;
    return p;
  };
  __half* P16a = (__half*)alloc((size_t)N * 128 * 2);
  __half* P16b = (__half*)alloc((size_t)N * 128 * 2);
  __half* wt2  = (__half*)alloc((size_t)1024 * 128 * 2);
  __half* wt3  = (__half*)alloc((size_t)1024 * 128 * 2);
  __half* rwt1 = (__half*)alloc((size_t)128 * 1024 * 2);
  __half* rwt2 = (__half*)alloc((size_t)128 * 1024 * 2);
  __half* lwt  = (__half*)alloc((size_t)128 * 1024 * 2);
  float* ws1 = (float*)alloc(8 * 4 * 4);
  float* wd1 = (float*)alloc(8 * 4 * 4);
  float* ws2 = (float*)alloc(8 * 128 * 4);
  float* wd2 = (float*)alloc(8 * 128 * 4);
  float* ws3 = (float*)alloc(8 * 128 * 4);
  float* wd3 = (float*)alloc(8 * 128 * 4);
  float* ssrcA = (float*)alloc((size_t)N * 8 * 4);
  float* sdstA = (float*)alloc((size_t)N * 8 * 4);
  float* ssrcB = (float*)alloc((size_t)N * 8 * 4);
  float* sdstB = (float*)alloc((size_t)N * 8 * 4);
  int* counts  = (int*)alloc((size_t)N * 4);
  int* offsets = (int*)alloc((size_t)(N + 1) * 4);
  int* cursor  = (int*)alloc((size_t)N * 4);
  int* srcs    = (int*)alloc((size_t)ET * 4);

  dim3 blk(THREADS);
  dim3 blk512(512);
  int nHist = (ET + THREADS - 1) / THREADS;

  hipMemsetAsync(counts, 0, (size_t)N * 4, stream);

  prep_kernel<<<dim3(nHist + 640 + 24), blk, 0, stream>>>(
      ei, E, ET, counts,
      w2, w3, rw1, rw2, lw, wt2, wt3, rwt1, rwt2, lwt,
      w1, as1, ad1, as2, ad2, as3, ad3,
      ws1, wd1, ws2, wd2, ws3, wd3, nHist);

  int total1 = N * 8;
  int nSc = (total1 + 1023) / 1024;
  scan_scores_kernel<<<dim3(1 + nSc), dim3(1024), 0, stream>>>(
      counts, offsets, cursor, N, x, ws1, wd1, ssrcA, sdstA, total1);

  scatter_kernel<<<dim3(nHist), blk, 0, stream>>>(ei, E, ET, cursor, srcs);

  dim3 gRow32(nRow32);

  // layer 1: reads ssrcA (layer-1 scores), writes P16a + ssrcB (layer-2 scores)
  layer1_kernel<<<gRow32, blk512, 0, stream>>>(
      x, srcs, offsets, ssrcA, sdstA, w1, b1, rwt1, rb1, P16a, N,
      ws2, wd2, ssrcB, sdstB);

  // layer 2: reads P16a + ssrcB, writes P16b + ssrcA (layer-3 scores)
  layer_p_kernel<__half, true><<<gRow32, blk512, 0, stream>>>(
      P16a, srcs, offsets, ssrcB, sdstB, wt2, b2, rwt2, rb2, P16b, N,
      ws3, wd3, ssrcA, sdstA);

  // layer 3: reads P16b + ssrcA, writes final output
  layer_p_kernel<float, false><<<gRow32, blk512, 0, stream>>>(
      P16b, srcs, offsets, ssrcA, sdstA, wt3, b3, lwt, lb, (float*)d_out, N,
      nullptr, nullptr, nullptr, nullptr);
}

// Round 3
// 284.501 us; speedup vs baseline: 1.0181x; 1.0181x over previous
//
#include <hip/hip_runtime.h>
#include <hip/hip_fp16.h>
#include <math.h>

// GAT encoder: N=10000, E=160000 (+N self loops), H=8 heads, C=128, D=1024.
// R17: dispatch fusion (prep, scan||scoresX, scoresP folded into tails).
// R18 (megafusion) REVERTED: 313-block fused layers dropped gather concurrency
// to 2504 waves / 20% occupancy -> 63.6us latency-bound layer kernels.
// R19: separate wave-per-node attnagg (10k waves, 32 waves/CU) + batch-8
// edge gather (8 outstanding P16 loads per wave vs 2) to hide L2/IC latency.

#define THREADS 256
#define CAP 128

typedef _Float16 f16x8 __attribute__((ext_vector_type(8)));
typedef float f32x4 __attribute__((ext_vector_type(4)));

struct __align__(8) Half4 { __half2 a, b; };

__device__ __forceinline__ float gelu_exact(float x) {
  return 0.5f * x * (1.0f + erff(x * 0.70710678118654752f));
}

// ---------------- fused prep: hist + weight transpose/convert + score-vectors ----------------

__global__ __launch_bounds__(256) void prep_kernel(
    const int* __restrict__ ei, int E, int ET, int* __restrict__ counts,
    const float* __restrict__ w2, const float* __restrict__ w3,
    const float* __restrict__ rw1, const float* __restrict__ rw2,
    const float* __restrict__ lw,
    __half* __restrict__ wt2, __half* __restrict__ wt3,
    __half* __restrict__ rwt1, __half* __restrict__ rwt2,
    __half* __restrict__ lwt,
    const float* __restrict__ w1,
    const float* __restrict__ as1, const float* __restrict__ ad1,
    const float* __restrict__ as2, const float* __restrict__ ad2,
    const float* __restrict__ as3, const float* __restrict__ ad3,
    float* __restrict__ ws1, float* __restrict__ wd1,
    float* __restrict__ ws2, float* __restrict__ wd2,
    float* __restrict__ ws3, float* __restrict__ wd3,
    int nHist) {
  __shared__ float tile[32][33];
  int bid = blockIdx.x;
  int t = threadIdx.x;

  if (bid < nHist) {
    int e = bid * 256 + t;
    if (e >= ET) return;
    int d = (e < E) ? ei[E + e] : (e - E);
    atomicAdd(&counts[d], 1);
    return;
  }
  bid -= nHist;
  if (bid < 640) {
    const float* in; __half* out; int K, Ncol;
    int z = bid >> 7, rem = bid & 127;
    switch (z) {
      case 0: in = w2;  out = wt2;  K = 128;  Ncol = 1024; break;
      case 1: in = w3;  out = wt3;  K = 128;  Ncol = 1024; break;
      case 2: in = rw1; out = rwt1; K = 1024; Ncol = 128;  break;
      case 3: in = rw2; out = rwt2; K = 1024; Ncol = 128;  break;
      default: in = lw; out = lwt;  K = 1024; Ncol = 128;  break;
    }
    int kt, ct;
    if (z < 2) { kt = rem >> 5; ct = rem & 31; }
    else       { kt = rem & 31; ct = rem >> 5; }
    int kb = kt * 32, cb = ct * 32;
    int tc = t & 31, tr = t >> 5;
#pragma unroll
    for (int r = tr; r < 32; r += 8)
      tile[r][tc] = in[(size_t)(kb + r) * Ncol + cb + tc];
    __syncthreads();
#pragma unroll
    for (int r = tr; r < 32; r += 8)
      out[(size_t)(cb + r) * K + kb + tc] = __float2half_rn(tile[tc][r]);
    return;
  }
  bid -= 640;
  {
    int h = bid & 7, yy = bid >> 3;
    int sel = t >> 7;
    int k = t & 127;
    const float* W; const float* av; float* outp; int K;
    switch (yy) {
      case 0: W = w2; av = sel ? ad2 : as2; outp = sel ? wd2 : ws2; K = 128; break;
      case 1: W = w3; av = sel ? ad3 : as3; outp = sel ? wd3 : ws3; K = 128; break;
      default: W = w1; av = sel ? ad1 : as1; outp = sel ? wd1 : ws1; K = 4; break;
    }
    if (k >= K) return;
    const float* wrow = W + (size_t)k * 1024 + h * 128;
    const float* arow = av + h * 128;
    float s = 0.f;
    for (int c = 0; c < 128; c += 4) {
      float4 wv = *(const float4*)&wrow[c];
      float4 a4 = *(const float4*)&arow[c];
      s += wv.x * a4.x + wv.y * a4.y + wv.z * a4.z + wv.w * a4.w;
    }
    outp[h * K + k] = s;
  }
}

// ---------------- scan (block 0) || layer-1 scores (blocks 1..) ----------------

__global__ __launch_bounds__(1024) void scan_scores_kernel(
    const int* __restrict__ counts, int* __restrict__ offsets,
    int* __restrict__ cursor, int n,
    const float* __restrict__ x,
    const float* __restrict__ ws1, const float* __restrict__ wd1,
    float* __restrict__ ssrc, float* __restrict__ sdst, int total) {
  __shared__ int sums[1024];
  if (blockIdx.x == 0) {
    int t = threadIdx.x;
    int per = (n + 1023) >> 10;
    int start = t * per; if (start > n) start = n;
    int end = start + per; if (end > n) end = n;
    int local = 0;
    for (int i = start; i < end; ++i) local += counts[i];
    sums[t] = local;
    __syncthreads();
    for (int off = 1; off < 1024; off <<= 1) {
      int add = (t >= off) ? sums[t - off] : 0;
      __syncthreads();
      sums[t] += add;
      __syncthreads();
    }
    int run = (t == 0) ? 0 : sums[t - 1];
    for (int i = start; i < end; ++i) {
      offsets[i] = run; cursor[i] = run; run += counts[i];
    }
    if (t == 1023) offsets[n] = run;
    return;
  }
  int idx = (blockIdx.x - 1) * 1024 + threadIdx.x;
  if (idx >= total) return;
  int nn = idx >> 3, h = idx & 7;
  float4 xv = *(const float4*)&x[nn * 4];
  float4 a = *(const float4*)&ws1[h * 4];
  float4 b = *(const float4*)&wd1[h * 4];
  ssrc[idx] = xv.x * a.x + xv.y * a.y + xv.z * a.z + xv.w * a.w;
  sdst[idx] = xv.x * b.x + xv.y * b.y + xv.z * b.z + xv.w * b.w;
}

__global__ void scatter_kernel(const int* __restrict__ ei, int E, int ET,
                               int* __restrict__ cursor, int* __restrict__ srcs) {
  int e = blockIdx.x * THREADS + threadIdx.x;
  if (e >= ET) return;
  int s = (e < E) ? ei[e] : (e - E);
  int d = (e < E) ? ei[E + e] : (e - E);
  int pos = atomicAdd(&cursor[d], 1);
  srcs[pos] = s;
}

// ---------------- fused attention + aggregation (P16), wave per node ----------------
// R19: aggregation in batches of 8 edges -- all 8 P16 loads issued before the
// FMA block so the wave keeps 8 gathers outstanding (latency hiding).

__global__ __launch_bounds__(256) void attnagg_p(const __half* __restrict__ P16,
                                                 const int* __restrict__ srcs,
                                                 const int* __restrict__ offsets,
                                                 const float* __restrict__ ssrc,
                                                 const float* __restrict__ sdst,
                                                 __half* __restrict__ Y16, int NP) {
  __shared__ float lal[4][CAP][8];
  __shared__ int ls[4][CAP];
  __shared__ float szinv[4][8];
  int w = threadIdx.x >> 6, lane = threadIdx.x & 63;
  int n = blockIdx.x * 4 + w;
  int start = offsets[n], deg = offsets[n + 1] - start;
  int head = lane & 7, es = lane >> 3;
  float sd = sdst[n * 8 + head];
  int c2 = lane * 2;
  const __half* pbase = P16 + c2;
  float accx[8] = {}, accy[8] = {};
  float s = 0.f;
  for (int cc = 0; cc < deg; cc += CAP) {
    int cm = min(CAP, deg - cc);
    for (int i = es; i < cm; i += 8) {
      int sp = srcs[start + cc + i];
      float v = ssrc[sp * 8 + head] + sd;
      v = (v > 0.f) ? v : 0.2f * v;
      float e = __expf(v);
      lal[w][i][head] = e;
      if (head == 0) ls[w][i] = sp;
      s += e;
    }
    int i = 0;
    for (; i + 8 <= cm; i += 8) {
      float2 pv[8];
#pragma unroll
      for (int u = 0; u < 8; ++u) {
        int sp = ls[w][i + u];
        pv[u] = __half22float2(*(const __half2*)&pbase[(size_t)sp * 128]);
      }
#pragma unroll
      for (int u = 0; u < 8; ++u) {
        float4 a00 = *(float4*)&lal[w][i + u][0];
        float4 a01 = *(float4*)&lal[w][i + u][4];
        float a0[8] = {a00.x, a00.y, a00.z, a00.w, a01.x, a01.y, a01.z, a01.w};
#pragma unroll
        for (int h = 0; h < 8; ++h) {
          accx[h] += a0[h] * pv[u].x; accy[h] += a0[h] * pv[u].y;
        }
      }
    }
    for (; i < cm; ++i) {
      int sp0 = ls[w][i];
      float2 p0 = __half22float2(*(const __half2*)&pbase[(size_t)sp0 * 128]);
      float4 a00 = *(float4*)&lal[w][i][0];
      float4 a01 = *(float4*)&lal[w][i][4];
      float a0[8] = {a00.x, a00.y, a00.z, a00.w, a01.x, a01.y, a01.z, a01.w};
#pragma unroll
      for (int h = 0; h < 8; ++h) {
        accx[h] += a0[h] * p0.x; accy[h] += a0[h] * p0.y;
      }
    }
  }
#pragma unroll
  for (int mask = 8; mask <= 32; mask <<= 1)
    s += __shfl_xor(s, mask);
  if (es == 0) szinv[w][head] = 1.f / s;
#pragma unroll
  for (int h = 0; h < 8; ++h) {
    float zi = szinv[w][h];
    *(__half2*)&Y16[((size_t)h * NP + n) * 128 + c2] =
        __floats2half2_rn(accx[h] * zi, accy[h] * zi);
  }
}

// ---------------- fused attention + aggregation (layer 1, raw x) ----------------

__global__ __launch_bounds__(256) void attnagg_x(const float* __restrict__ x,
                                                 const int* __restrict__ srcs,
                                                 const int* __restrict__ offsets,
                                                 const float* __restrict__ ssrc,
                                                 const float* __restrict__ sdst,
                                                 float* __restrict__ Y1, int NP) {
  __shared__ float lal[4][CAP][8];
  __shared__ int ls[4][CAP];
  __shared__ float szinv[4][8];
  int w = threadIdx.x >> 6, lane = threadIdx.x & 63;
  int n = blockIdx.x * 4 + w;
  int start = offsets[n], deg = offsets[n + 1] - start;
  int head = lane & 7, es = lane >> 3;
  float sd = sdst[n * 8 + head];
  int eo = lane >> 5, hb = (lane >> 2) & 7, ch = lane & 3;
  float acc = 0.f;
  float s = 0.f;
  for (int cc = 0; cc < deg; cc += CAP) {
    int cm = min(CAP, deg - cc);
    for (int i = es; i < cm; i += 8) {
      int sp = srcs[start + cc + i];
      float v = ssrc[sp * 8 + head] + sd;
      v = (v > 0.f) ? v : 0.2f * v;
      float e = __expf(v);
      lal[w][i][head] = e;
      if (head == 0) ls[w][i] = sp;
      s += e;
    }
    // batch-4 gather: this lane handles edges eo, eo+2, eo+4, ... (stride 2)
    int i = eo;
    for (; i + 6 < cm; i += 8) {
      float xv[4]; float av[4];
#pragma unroll
      for (int u = 0; u < 4; ++u) {
        int sp = ls[w][i + 2 * u];
        xv[u] = x[sp * 4 + ch];
      }
#pragma unroll
      for (int u = 0; u < 4; ++u) av[u] = lal[w][i + 2 * u][hb];
#pragma unroll
      for (int u = 0; u < 4; ++u) acc += av[u] * xv[u];
    }
    for (; i < cm; i += 2) {
      int sp = ls[w][i];
      acc += lal[w][i][hb] * x[sp * 4 + ch];
    }
  }
#pragma unroll
  for (int mask = 8; mask <= 32; mask <<= 1)
    s += __shfl_xor(s, mask);
  if (es == 0) szinv[w][head] = 1.f / s;
  acc += __shfl_xor(acc, 32);
  if (lane < 32) {
    float zi = szinv[w][hb];
    Y1[((size_t)hb * NP + n) * 4 + ch] = acc * zi;
  }
}

// ---------------- fused tail (layers 2/3), 512 threads, 32 rows, row-blocked ----------------

template <typename OutT, bool SC>
__global__ __launch_bounds__(512) void tail_mfma(const __half* __restrict__ Y16,
                                                 const __half* __restrict__ WtA,
                                                 const float* __restrict__ biasA,
                                                 const __half* __restrict__ WtP,
                                                 const float* __restrict__ biasP,
                                                 OutT* __restrict__ out, int N, int NP,
                                                 const float* __restrict__ wsn,
                                                 const float* __restrict__ wdn,
                                                 float* __restrict__ ssrc,
                                                 float* __restrict__ sdst) {
  __shared__ __half Gt[32][1032];
  __shared__ __half Pl[32][136];
  int w = threadIdx.x >> 6, lane = threadIdx.x & 63;
  int r0 = blockIdx.x * 32;
  int m = lane & 15, quad = lane >> 4;
  // stage 1
  {
    int h = w;
    const __half* py0 = Y16 + ((size_t)h * NP + r0 + m) * 128 + quad * 8;
    const __half* py1 = py0 + (size_t)16 * 128;
    f16x8 bf0[4], bf1[4];
#pragma unroll
    for (int kk = 0; kk < 4; ++kk) {
      bf0[kk] = *(const f16x8*)(py0 + kk * 32);
      bf1[kk] = *(const f16x8*)(py1 + kk * 32);
    }
#pragma unroll
    for (int tile = 0; tile < 8; ++tile) {
      int gc = h * 128 + tile * 16;
      const __half* pa = WtA + (size_t)(gc + m) * 128 + quad * 8;
      f16x8 a[4];
#pragma unroll
      for (int kk = 0; kk < 4; ++kk) a[kk] = *(const f16x8*)(pa + kk * 32);
      f32x4 acc0 = {0.f, 0.f, 0.f, 0.f}, acc1 = {0.f, 0.f, 0.f, 0.f};
#pragma unroll
      for (int kk = 0; kk < 4; ++kk) {
        acc0 = __builtin_amdgcn_mfma_f32_16x16x32_f16(a[kk], bf0[kk], acc0, 0, 0, 0);
        acc1 = __builtin_amdgcn_mfma_f32_16x16x32_f16(a[kk], bf1[kk], acc1, 0, 0, 0);
      }
      float4 b4 = *(const float4*)&biasA[gc + quad * 4];
      Half4 p0, p1;
      p0.a = __floats2half2_rn(gelu_exact(acc0[0] + b4.x), gelu_exact(acc0[1] + b4.y));
      p0.b = __floats2half2_rn(gelu_exact(acc0[2] + b4.z), gelu_exact(acc0[3] + b4.w));
      p1.a = __floats2half2_rn(gelu_exact(acc1[0] + b4.x), gelu_exact(acc1[1] + b4.y));
      p1.b = __floats2half2_rn(gelu_exact(acc1[2] + b4.z), gelu_exact(acc1[3] + b4.w));
      *(Half4*)&Gt[m][gc + quad * 4] = p0;
      *(Half4*)&Gt[16 + m][gc + quad * 4] = p1;
    }
  }
  __syncthreads();
  // stage 2
  {
    int c0 = w * 16;
    const __half* pa = WtP + (size_t)(c0 + m) * 1024 + quad * 8;
    f32x4 acc0 = {0.f, 0.f, 0.f, 0.f}, acc1 = {0.f, 0.f, 0.f, 0.f};
#pragma unroll 8
    for (int k = 0; k < 1024; k += 32) {
      f16x8 a = *(const f16x8*)(pa + k);
      f16x8 b0 = *(const f16x8*)&Gt[m][quad * 8 + k];
      f16x8 b1 = *(const f16x8*)&Gt[16 + m][quad * 8 + k];
      acc0 = __builtin_amdgcn_mfma_f32_16x16x32_f16(a, b0, acc0, 0, 0, 0);
      acc1 = __builtin_amdgcn_mfma_f32_16x16x32_f16(a, b1, acc1, 0, 0, 0);
    }
    float4 b4 = *(const float4*)&biasP[c0 + quad * 4];
    int row0 = r0 + m, row1 = r0 + 16 + m;
    if constexpr (__is_same(OutT, __half)) {
      Half4 p, q;
      p.a = __floats2half2_rn(acc0[0] + b4.x, acc0[1] + b4.y);
      p.b = __floats2half2_rn(acc0[2] + b4.z, acc0[3] + b4.w);
      q.a = __floats2half2_rn(acc1[0] + b4.x, acc1[1] + b4.y);
      q.b = __floats2half2_rn(acc1[2] + b4.z, acc1[3] + b4.w);
      if constexpr (SC) {
        *(Half4*)&Pl[m][c0 + quad * 4] = p;
        *(Half4*)&Pl[16 + m][c0 + quad * 4] = q;
      }
      if (row0 < N) *(Half4*)&out[(size_t)row0 * 128 + c0 + quad * 4] = p;
      if (row1 < N) *(Half4*)&out[(size_t)row1 * 128 + c0 + quad * 4] = q;
    } else {
      if (row0 < N)
        *(float4*)&out[(size_t)row0 * 128 + c0 + quad * 4] =
            make_float4(acc0[0] + b4.x, acc0[1] + b4.y, acc0[2] + b4.z, acc0[3] + b4.w);
      if (row1 < N)
        *(float4*)&out[(size_t)row1 * 128 + c0 + quad * 4] =
            make_float4(acc1[0] + b4.x, acc1[1] + b4.y, acc1[2] + b4.z, acc1[3] + b4.w);
    }
  }
  if constexpr (SC) {
    __syncthreads();
    int head = lane & 7, es = lane >> 3;
    const float* wsp = wsn + head * 128 + es * 16;
    const float* wdp = wdn + head * 128 + es * 16;
    float wsr[16], wdr[16];
#pragma unroll
    for (int j = 0; j < 16; ++j) { wsr[j] = wsp[j]; wdr[j] = wdp[j]; }
#pragma unroll
    for (int r = 0; r < 4; ++r) {
      int row = w * 4 + r;
      f16x8 p0 = *(const f16x8*)&Pl[row][es * 16];
      f16x8 p1 = *(const f16x8*)&Pl[row][es * 16 + 8];
      float s1 = 0.f, s2 = 0.f;
#pragma unroll
      for (int j = 0; j < 8; ++j) {
        float v = (float)p0[j];
        s1 += v * wsr[j]; s2 += v * wdr[j];
      }
#pragma unroll
      for (int j = 0; j < 8; ++j) {
        float v = (float)p1[j];
        s1 += v * wsr[8 + j]; s2 += v * wdr[8 + j];
      }
#pragma unroll
      for (int mask = 8; mask <= 32; mask <<= 1) {
        s1 += __shfl_xor(s1, mask);
        s2 += __shfl_xor(s2, mask);
      }
      int nn = r0 + row;
      if (es == 0 && nn < N) { ssrc[nn * 8 + head] = s1; sdst[nn * 8 + head] = s2; }
    }
  }
}

// ---------------- fused tail (layer 1), 512 threads, 32 rows ----------------

template <typename OutT, bool SC>
__global__ __launch_bounds__(512) void tail1_kernel(const float* __restrict__ Y1,
                                                    const float* __restrict__ w,
                                                    const float* __restrict__ biasA,
                                                    const __half* __restrict__ WtP,
                                                    const float* __restrict__ biasP,
                                                    OutT* __restrict__ out, int N, int NP,
                                                    const float* __restrict__ wsn,
                                                    const float* __restrict__ wdn,
                                                    float* __restrict__ ssrc,
                                                    float* __restrict__ sdst) {
  __shared__ __half Gt[32][1032];
  __shared__ __half Pl[32][136];
  int t = threadIdx.x;
  int r0 = blockIdx.x * 32;
  {
    int c0 = (t & 255) * 4;
    int h = c0 >> 7;
    float4 wa = *(const float4*)&w[c0];
    float4 wb = *(const float4*)&w[1024 + c0];
    float4 wc = *(const float4*)&w[2048 + c0];
    float4 wd = *(const float4*)&w[3072 + c0];
    float4 b4 = *(const float4*)&biasA[c0];
#pragma unroll 4
    for (int r = t >> 8; r < 32; r += 2) {
      float4 yv = *(const float4*)&Y1[((size_t)h * NP + r0 + r) * 4];
      float o0 = gelu_exact(yv.x * wa.x + yv.y * wb.x + yv.z * wc.x + yv.w * wd.x + b4.x);
      float o1 = gelu_exact(yv.x * wa.y + yv.y * wb.y + yv.z * wc.y + yv.w * wd.y + b4.y);
      float o2 = gelu_exact(yv.x * wa.z + yv.y * wb.z + yv.z * wc.z + yv.w * wd.z + b4.z);
      float o3 = gelu_exact(yv.x * wa.w + yv.y * wb.w + yv.z * wc.w + yv.w * wd.w + b4.w);
      Half4 p;
      p.a = __floats2half2_rn(o0, o1);
      p.b = __floats2half2_rn(o2, o3);
      *(Half4*)&Gt[r][c0] = p;
    }
  }
  __syncthreads();
  int wv = t >> 6, lane = t & 63;
  int m = lane & 15, quad = lane >> 4;
  {
    int c0 = wv * 16;
    const __half* pa = WtP + (size_t)(c0 + m) * 1024 + quad * 8;
    f32x4 acc0 = {0.f, 0.f, 0.f, 0.f}, acc1 = {0.f, 0.f, 0.f, 0.f};
#pragma unroll 8
    for (int k = 0; k < 1024; k += 32) {
      f16x8 a = *(const f16x8*)(pa + k);
      f16x8 b0 = *(const f16x8*)&Gt[m][quad * 8 + k];
      f16x8 b1 = *(const f16x8*)&Gt[16 + m][quad * 8 + k];
      acc0 = __builtin_amdgcn_mfma_f32_16x16x32_f16(a, b0, acc0, 0, 0, 0);
      acc1 = __builtin_amdgcn_mfma_f32_16x16x32_f16(a, b1, acc1, 0, 0, 0);
    }
    float4 b4 = *(const float4*)&biasP[c0 + quad * 4];
    int row0 = r0 + m, row1 = r0 + 16 + m;
    if constexpr (__is_same(OutT, __half)) {
      Half4 p, q;
      p.a = __floats2half2_rn(acc0[0] + b4.x, acc0[1] + b4.y);
      p.b = __floats2half2_rn(acc0[2] + b4.z, acc0[3] + b4.w);
      q.a = __floats2half2_rn(acc1[0] + b4.x, acc1[1] + b4.y);
      q.b = __floats2half2_rn(acc1[2] + b4.z, acc1[3] + b4.w);
      if constexpr (SC) {
        *(Half4*)&Pl[m][c0 + quad * 4] = p;
        *(Half4*)&Pl[16 + m][c0 + quad * 4] = q;
      }
      if (row0 < N) *(Half4*)&out[(size_t)row0 * 128 + c0 + quad * 4] = p;
      if (row1 < N) *(Half4*)&out[(size_t)row1 * 128 + c0 + quad * 4] = q;
    } else {
      if (row0 < N)
        *(float4*)&out[(size_t)row0 * 128 + c0 + quad * 4] =
            make_float4(acc0[0] + b4.x, acc0[1] + b4.y, acc0[2] + b4.z, acc0[3] + b4.w);
      if (row1 < N)
        *(float4*)&out[(size_t)row1 * 128 + c0 + quad * 4] =
            make_float4(acc1[0] + b4.x, acc1[1] + b4.y, acc1[2] + b4.z, acc1[3] + b4.w);
    }
  }
  if constexpr (SC) {
    __syncthreads();
    int head = lane & 7, es = lane >> 3;
    const float* wsp = wsn + head * 128 + es * 16;
    const float* wdp = wdn + head * 128 + es * 16;
    float wsr[16], wdr[16];
#pragma unroll
    for (int j = 0; j < 16; ++j) { wsr[j] = wsp[j]; wdr[j] = wdp[j]; }
#pragma unroll
    for (int r = 0; r < 4; ++r) {
      int row = wv * 4 + r;
      f16x8 p0 = *(const f16x8*)&Pl[row][es * 16];
      f16x8 p1 = *(const f16x8*)&Pl[row][es * 16 + 8];
      float s1 = 0.f, s2 = 0.f;
#pragma unroll
      for (int j = 0; j < 8; ++j) {
        float v = (float)p0[j];
        s1 += v * wsr[j]; s2 += v * wdr[j];
      }
#pragma unroll
      for (int j = 0; j < 8; ++j) {
        float v = (float)p1[j];
        s1 += v * wsr[8 + j]; s2 += v * wdr[8 + j];
      }
#pragma unroll
      for (int mask = 8; mask <= 32; mask <<= 1) {
        s1 += __shfl_xor(s1, mask);
        s2 += __shfl_xor(s2, mask);
      }
      int nn = r0 + row;
      if (es == 0 && nn < N) { ssrc[nn * 8 + head] = s1; sdst[nn * 8 + head] = s2; }
    }
  }
}

// ---------------- orchestration ----------------

extern "C" void kernel_launch(void* const* d_in, const int* in_sizes, int n_in,
                              void* d_out, int out_size, void* d_ws, size_t ws_size,
                              hipStream_t stream) {
  const float* x   = (const float*)d_in[0];
  const int*   ei  = (const int*)d_in[1];
  const float* w1  = (const float*)d_in[2];
  const float* as1 = (const float*)d_in[3];
  const float* ad1 = (const float*)d_in[4];
  const float* b1  = (const float*)d_in[5];
  const float* w2  = (const float*)d_in[6];
  const float* as2 = (const float*)d_in[7];
  const float* ad2 = (const float*)d_in[8];
  const float* b2  = (const float*)d_in[9];
  const float* w3  = (const float*)d_in[10];
  const float* as3 = (const float*)d_in[11];
  const float* ad3 = (const float*)d_in[12];
  const float* b3  = (const float*)d_in[13];
  const float* rw1 = (const float*)d_in[14];
  const float* rb1 = (const float*)d_in[15];
  const float* rw2 = (const float*)d_in[16];
  const float* rb2 = (const float*)d_in[17];
  const float* lw  = (const float*)d_in[18];
  const float* lb  = (const float*)d_in[19];

  int N = in_sizes[0] / 4;
  int E = in_sizes[1] / 2;
  int ET = E + N;
  int nRow32 = (N + 31) / 32;
  int NP = nRow32 * 32;          // padded rows (10016)
  (void)ws_size;

  char* wsb = (char*)d_ws;
  size_t off = 0;
  auto alloc = [&](size_t bytes) -> void* {
    void* p = wsb + off;
    off += (bytes + 255) & ~(size_t)255;
    return p;
  };
  __half* P16  = (__half*)alloc((size_t)N * 128 * 2);
  __half* Y16  = (__half*)alloc((size_t)8 * NP * 128 * 2);
  float*  Y1   = (float*)alloc((size_t)8 * NP * 4 * 4);
  __half* wt2  = (__half*)alloc((size_t)1024 * 128 * 2);
  __half* wt3  = (__half*)alloc((size_t)1024 * 128 * 2);
  __half* rwt1 = (__half*)alloc((size_t)128 * 1024 * 2);
  __half* rwt2 = (__half*)alloc((size_t)128 * 1024 * 2);
  __half* lwt  = (__half*)alloc((size_t)128 * 1024 * 2);
  float* ws1 = (float*)alloc(8 * 4 * 4);
  float* wd1 = (float*)alloc(8 * 4 * 4);
  float* ws2 = (float*)alloc(8 * 128 * 4);
  float* wd2 = (float*)alloc(8 * 128 * 4);
  float* ws3 = (float*)alloc(8 * 128 * 4);
  float* wd3 = (float*)alloc(8 * 128 * 4);
  float* ssrc   = (float*)alloc((size_t)N * 8 * 4);
  float* sdst   = (float*)alloc((size_t)N * 8 * 4);
  int* counts  = (int*)alloc((size_t)N * 4);
  int* offsets = (int*)alloc((size_t)(N + 1) * 4);
  int* cursor  = (int*)alloc((size_t)N * 4);
  int* srcs    = (int*)alloc((size_t)ET * 4);

  dim3 blk(THREADS);
  dim3 blk512(512);
  int nHist = (ET + THREADS - 1) / THREADS;

  hipMemsetAsync(counts, 0, (size_t)N * 4, stream);

  prep_kernel<<<dim3(nHist + 640 + 24), blk, 0, stream>>>(
      ei, E, ET, counts,
      w2, w3, rw1, rw2, lw, wt2, wt3, rwt1, rwt2, lwt,
      w1, as1, ad1, as2, ad2, as3, ad3,
      ws1, wd1, ws2, wd2, ws3, wd3, nHist);

  int total1 = N * 8;
  int nSc = (total1 + 1023) / 1024;
  scan_scores_kernel<<<dim3(1 + nSc), dim3(1024), 0, stream>>>(
      counts, offsets, cursor, N, x, ws1, wd1, ssrc, sdst, total1);

  scatter_kernel<<<dim3(nHist), blk, 0, stream>>>(ei, E, ET, cursor, srcs);

  dim3 gNode4(N / 4);
  dim3 gRow32(nRow32);

  // ---- layer 1 ----
  attnagg_x<<<gNode4, blk, 0, stream>>>(x, srcs, offsets, ssrc, sdst, Y1, NP);
  tail1_kernel<__half, true><<<gRow32, blk512, 0, stream>>>(
      Y1, w1, b1, rwt1, rb1, P16, N, NP, ws2, wd2, ssrc, sdst);

  // ---- layer 2 ----
  attnagg_p<<<gNode4, blk, 0, stream>>>(P16, srcs, offsets, ssrc, sdst, Y16, NP);
  tail_mfma<__half, true><<<gRow32, blk512, 0, stream>>>(
      Y16, wt2, b2, rwt2, rb2, P16, N, NP, ws3, wd3, ssrc, sdst);

  // ---- layer 3 ----
  attnagg_p<<<gNode4, blk, 0, stream>>>(P16, srcs, offsets, ssrc, sdst, Y16, NP);
  tail_mfma<float, false><<<gRow32, blk512, 0, stream>>>(
      Y16, wt3, b3, lwt, lb, (float*)d_out, N, NP, nullptr, nullptr, nullptr, nullptr);
}